// Round 5
// baseline (86.297 us; speedup 1.0000x reference)
//
#include <hip/hip_runtime.h>
#include <hip/hip_cooperative_groups.h>
#include <stdint.h>

namespace cg = cooperative_groups;

#define D_ 128
#define HW_ 65536          // 256*256
#define K_ 4
#define NBC 4
#define PAIRS_PER_BC (HW_/2)   // 32768 float2 column-pairs per (b,c)
#define NBLK 512
#define BLK_PER_BC (NBLK/NBC)  // 128 blocks per (b,c)
#define SCALE_ 100000.0f
#define EPS_ 1e-15f

// One cooperative kernel:
//  Phase A: per-thread (2 columns, float2 loads) raw top-4 + raw min/max scan.
//           Block reduce min/max -> ws[block] (plain store, no atomics/init).
//  grid.sync()  (top-4 state lives in registers across it)
//  Phase B: every block reduces the 128 partials OF ITS OWN (b,c) (min/max is
//           per (b,c)!), normalizes its register top-4 (relu applied here;
//           monotonicity => same selection), writes out.
__global__ __launch_bounds__(256, 2)
void fused_kernel(const float* __restrict__ x, float* __restrict__ out,
                  float2* __restrict__ ws) {
    const int gt = blockIdx.x * 256 + threadIdx.x;    // pair id 0..131071
    const int bc = gt >> 15;                          // / PAIRS_PER_BC
    const int pr = gt & (PAIRS_PER_BC - 1);

    const float2* __restrict__ src =
        (const float2*)(x + (size_t)bc * (D_ * HW_)) + pr;

    // raw-value top-4 per column, sorted desc; strict > with ascending d
    // == lax.top_k tie-break (earliest depth wins ties)
    float lv[2][K_];
    int   li[2][K_];
    #pragma unroll
    for (int j = 0; j < 2; ++j)
        #pragma unroll
        for (int k = 0; k < K_; ++k) { lv[j][k] = -3.0e38f; li[j][k] = 0; }
    float mnraw = 3.0e38f;

    #pragma unroll 8
    for (int d = 0; d < D_; ++d) {
        const float2 q = src[(size_t)d * (HW_ / 2)];
        const float vx[2] = { q.x, q.y };
        mnraw = fminf(mnraw, fminf(q.x, q.y));
        #pragma unroll
        for (int j = 0; j < 2; ++j) {
            const float v = vx[j];
            const bool ins = v > lv[j][3];
            lv[j][3] = ins ? v : lv[j][3];
            li[j][3] = ins ? d : li[j][3];
            #pragma unroll
            for (int k = 3; k > 0; --k) {
                const bool sw = lv[j][k] > lv[j][k-1];
                const float tv = sw ? lv[j][k-1] : lv[j][k];
                const int   ti = sw ? li[j][k-1] : li[j][k];
                lv[j][k-1] = sw ? lv[j][k] : lv[j][k-1];
                li[j][k-1] = sw ? li[j][k] : li[j][k-1];
                lv[j][k] = tv;  li[j][k] = ti;
            }
        }
    }

    // ---- block reduce raw min / raw max -> ws[blockIdx.x] ----
    float mn = mnraw;
    float mx = fmaxf(lv[0][0], lv[1][0]);
    #pragma unroll
    for (int off = 32; off > 0; off >>= 1) {
        mn = fminf(mn, __shfl_xor(mn, off));
        mx = fmaxf(mx, __shfl_xor(mx, off));
    }
    __shared__ float smn[4], smx[4];
    const int wave = threadIdx.x >> 6;
    if ((threadIdx.x & 63) == 0) { smn[wave] = mn; smx[wave] = mx; }
    __syncthreads();
    if (threadIdx.x == 0) {
        float bmn = fminf(fminf(smn[0], smn[1]), fminf(smn[2], smn[3]));
        float bmx = fmaxf(fmaxf(smx[0], smx[1]), fmaxf(smx[2], smx[3]));
        ws[blockIdx.x] = make_float2(bmn, bmx);
    }

    cg::this_grid().sync();

    // ---- reduce the 128 partials of THIS (b,c) only (4 KB, L2-resident) ----
    {
        const int t = threadIdx.x;
        // 256 threads read the 128 entries twice each — harmless for min/max
        const float2 a = ws[(bc << 7) + (t & (BLK_PER_BC - 1))];
        mn = a.x;
        mx = a.y;
        #pragma unroll
        for (int off = 32; off > 0; off >>= 1) {
            mn = fminf(mn, __shfl_xor(mn, off));
            mx = fmaxf(mx, __shfl_xor(mx, off));
        }
        __syncthreads();   // smn/smx reuse
        if ((threadIdx.x & 63) == 0) { smn[wave] = mn; smx[wave] = mx; }
        __syncthreads();
        mn = fminf(fminf(smn[0], smn[1]), fminf(smn[2], smn[3]));
        mx = fmaxf(fmaxf(smx[0], smx[1]), fmaxf(smx[2], smx[3]));
    }

    // relu commutes with min/max (monotone): min/max of relu'd data
    const float mnf = fmaxf(mn, 0.0f);
    const float mxf = fmaxf(mx, 0.0f);
    const float scl = SCALE_ / ((mxf - mnf) + EPS_);

    // ---- normalize + write: pred ch then dep ch, float2 coalesced stores ----
    float2* out2 = (float2*)out;
    const size_t pbase = (size_t)(bc * 2 * K_) * (HW_ / 2) + pr;       // pred
    const size_t dbase = (size_t)((bc * 2 + 1) * K_) * (HW_ / 2) + pr; // dep
    #pragma unroll
    for (int k = 0; k < K_; ++k) {
        float2 pv, dv;
        pv.x = (fmaxf(lv[0][k], 0.0f) - mnf) * scl;
        pv.y = (fmaxf(lv[1][k], 0.0f) - mnf) * scl;
        dv.x = (float)(D_ - 1 - li[0][k]) * (1.0f / 127.0f);
        dv.y = (float)(D_ - 1 - li[1][k]) * (1.0f / 127.0f);
        out2[pbase + (size_t)k * (HW_ / 2)] = pv;
        out2[dbase + (size_t)k * (HW_ / 2)] = dv;
    }
}

extern "C" void kernel_launch(void* const* d_in, const int* in_sizes, int n_in,
                              void* d_out, int out_size, void* d_ws, size_t ws_size,
                              hipStream_t stream) {
    const float* x = (const float*)d_in[0];
    float* out = (float*)d_out;
    float2* ws = (float2*)d_ws;

    void* args[] = { (void*)&x, (void*)&out, (void*)&ws };
    hipLaunchCooperativeKernel((void*)fused_kernel, dim3(NBLK), dim3(256),
                               args, 0, stream);
}

// Round 7
// 40.396 us; speedup vs baseline: 2.1363x; 2.1363x over previous
//
#include <hip/hip_runtime.h>
#include <stdint.h>

#define D_ 128
#define HW_ 65536
#define GPB (HW_/4)            // 16384 float4 groups per depth-slice per (b,c)
#define K_ 4
#define NBC 4
#define NBLK 1024
#define SCALE_ 100000.0f
#define EPS_ 1e-15f

typedef unsigned long long u64;

__device__ __forceinline__ u64 umax64(u64 a, u64 b) { return a > b ? a : b; }
__device__ __forceinline__ void cswap(u64& hi, u64& lo) {
    u64 a = hi, b = lo; bool s = b > a; hi = s ? b : a; lo = s ? a : b;
}
// merge two desc-sorted 4-lists, keep top-4 (bitonic)
__device__ __forceinline__ void merge4(u64 a[4], const u64* b) {
    u64 m0 = umax64(a[0], b[3]);
    u64 m1 = umax64(a[1], b[2]);
    u64 m2 = umax64(a[2], b[1]);
    u64 m3 = umax64(a[3], b[0]);
    cswap(m0, m2); cswap(m1, m3); cswap(m0, m1); cswap(m2, m3);
    a[0] = m0; a[1] = m1; a[2] = m2; a[3] = m3;
}

// Block = 64 float4 col-groups; wave w (of 4) scans depth quarter w.
// Every wave-load: 64 lanes x float4 = 1 KB contiguous. float4 q[4] batches
// force 4 independent loads in flight. Quarters merged via LDS u64 keys.
// Writes raw pred values + final dep channel + per-block min/max -> ws[b].
__global__ __launch_bounds__(256, 4)
void topk_kernel(const float* __restrict__ x, float* __restrict__ out,
                 float2* __restrict__ ws) {
    const int b    = blockIdx.x;
    const int wv   = threadIdx.x >> 6;        // depth quarter 0..3
    const int lane = threadIdx.x & 63;
    const int bc   = b >> 8;                  // 256 blocks per (b,c)
    const int gg   = ((b & 255) << 6) | lane; // col-group within (b,c)

    const float4* __restrict__ src = (const float4*)x
        + (size_t)bc * (D_ * GPB) + (size_t)(wv * 32) * GPB + gg;

    // per-column top-4 of relu'd values, sorted desc; strict > keeps earliest d
    float lv[4][K_]; int li[4][K_];
    #pragma unroll
    for (int j = 0; j < 4; ++j)
        #pragma unroll
        for (int k = 0; k < K_; ++k) { lv[j][k] = -1.0f; li[j][k] = 0; }
    float mn = __int_as_float(0x7F800000);    // +inf (min of relu'd values)

    const int dbase = wv * 32;
    #pragma unroll 2
    for (int batch = 0; batch < 8; ++batch) {
        float4 q[4];
        #pragma unroll
        for (int j = 0; j < 4; ++j)
            q[j] = src[(size_t)(batch * 4 + j) * GPB];
        #pragma unroll
        for (int j = 0; j < 4; ++j) {
            const int d = dbase + batch * 4 + j;
            const float vx[4] = { fmaxf(q[j].x, 0.0f), fmaxf(q[j].y, 0.0f),
                                  fmaxf(q[j].z, 0.0f), fmaxf(q[j].w, 0.0f) };
            mn = fminf(mn, fminf(fminf(vx[0], vx[1]), fminf(vx[2], vx[3])));
            #pragma unroll
            for (int c = 0; c < 4; ++c) {
                const float v = vx[c];
                const bool ins = v > lv[c][3];
                lv[c][3] = ins ? v : lv[c][3];
                li[c][3] = ins ? d : li[c][3];
                #pragma unroll
                for (int k = 3; k > 0; --k) {
                    const bool sw = lv[c][k] > lv[c][k-1];
                    const float tv = sw ? lv[c][k-1] : lv[c][k];
                    const int   ti = sw ? li[c][k-1] : li[c][k];
                    lv[c][k-1] = sw ? lv[c][k] : lv[c][k-1];
                    li[c][k-1] = sw ? li[c][k] : li[c][k-1];
                    lv[c][k] = tv;  li[c][k] = ti;
                }
            }
        }
    }

    // ---- block min/max reduce -> ws[b] (plain store, no atomics) ----
    {
        float bmn = mn;
        float bmx = fmaxf(fmaxf(lv[0][0], lv[1][0]), fmaxf(lv[2][0], lv[3][0]));
        #pragma unroll
        for (int off = 32; off > 0; off >>= 1) {
            bmn = fminf(bmn, __shfl_xor(bmn, off));
            bmx = fmaxf(bmx, __shfl_xor(bmx, off));
        }
        __shared__ float smn[4], smx[4];
        if (lane == 0) { smn[wv] = bmn; smx[wv] = bmx; }
        __syncthreads();
        if (threadIdx.x == 0) {
            ws[b] = make_float2(
                fminf(fminf(smn[0], smn[1]), fminf(smn[2], smn[3])),
                fmaxf(fmaxf(smx[0], smx[1]), fmaxf(smx[2], smx[3])));
        }
    }

    // ---- pack u64 keys: (value_bits<<32) | (127 - idx); values >= 0 ----
    u64 key[4][K_];
    #pragma unroll
    for (int c = 0; c < 4; ++c)
        #pragma unroll
        for (int k = 0; k < K_; ++k)
            key[c][k] = ((u64)__float_as_uint(lv[c][k]) << 32)
                      | (unsigned int)(D_ - 1 - li[c][k]);

    // ---- merge the 4 depth-quarters via LDS (2 stages) ----
    __shared__ u64 sk[2][64][16];
    if (wv >= 2) {
        #pragma unroll
        for (int c = 0; c < 4; ++c)
            #pragma unroll
            for (int k = 0; k < K_; ++k)
                sk[wv - 2][lane][c * 4 + k] = key[c][k];
    }
    __syncthreads();
    if (wv < 2) {
        #pragma unroll
        for (int c = 0; c < 4; ++c)
            merge4(key[c], &sk[wv][lane][c * 4]);
    }
    __syncthreads();
    if (wv == 1) {
        #pragma unroll
        for (int c = 0; c < 4; ++c)
            #pragma unroll
            for (int k = 0; k < K_; ++k)
                sk[0][lane][c * 4 + k] = key[c][k];
    }
    __syncthreads();

    // ---- wave 0: write raw pred values + final dep channel ----
    if (wv == 0) {
        #pragma unroll
        for (int c = 0; c < 4; ++c)
            merge4(key[c], &sk[0][lane][c * 4]);

        float4* out4 = (float4*)out;
        const size_t pb = (size_t)(bc * 2 * K_) * GPB + gg;   // pred channel
        const size_t db = pb + (size_t)K_ * GPB;              // dep channel
        #pragma unroll
        for (int k = 0; k < K_; ++k) {
            float4 pv, dv;
            pv.x = __uint_as_float((unsigned int)(key[0][k] >> 32));
            pv.y = __uint_as_float((unsigned int)(key[1][k] >> 32));
            pv.z = __uint_as_float((unsigned int)(key[2][k] >> 32));
            pv.w = __uint_as_float((unsigned int)(key[3][k] >> 32));
            dv.x = (float)(int)(key[0][k] & 0xFFu) * (1.0f / 127.0f);
            dv.y = (float)(int)(key[1][k] & 0xFFu) * (1.0f / 127.0f);
            dv.z = (float)(int)(key[2][k] & 0xFFu) * (1.0f / 127.0f);
            dv.w = (float)(int)(key[3][k] & 0xFFu) * (1.0f / 127.0f);
            out4[pb + (size_t)k * GPB] = pv;
            out4[db + (size_t)k * GPB] = dv;
        }
    }
}

// Block reduces its (b,c)'s 256 ws partials (L2-resident), then normalizes
// one float4 of the pred channel in place.
__global__ __launch_bounds__(256)
void norm_kernel(float* __restrict__ out, const float2* __restrict__ ws) {
    const int b  = blockIdx.x;
    const int t  = threadIdx.x;
    const int bc = b >> 8;                    // 256 blocks per (b,c)

    const float2 a = ws[(bc << 8) + t];       // exactly the 256 partials of bc
    float mn = a.x, mx = a.y;
    #pragma unroll
    for (int off = 32; off > 0; off >>= 1) {
        mn = fminf(mn, __shfl_xor(mn, off));
        mx = fmaxf(mx, __shfl_xor(mx, off));
    }
    __shared__ float smn[4], smx[4];
    const int wv = t >> 6;
    if ((t & 63) == 0) { smn[wv] = mn; smx[wv] = mx; }
    __syncthreads();
    mn = fminf(fminf(smn[0], smn[1]), fminf(smn[2], smn[3]));
    mx = fmaxf(fmaxf(smx[0], smx[1]), fmaxf(smx[2], smx[3]));
    const float scl = SCALE_ / ((mx - mn) + EPS_);

    const int i = ((b & 255) << 8) | t;       // 0..65535 within bc's pred ch
    float4* out4 = (float4*)out;
    const size_t idx = (size_t)(bc * 2 * K_) * GPB + i;
    float4 v = out4[idx];
    v.x = (v.x - mn) * scl;
    v.y = (v.y - mn) * scl;
    v.z = (v.z - mn) * scl;
    v.w = (v.w - mn) * scl;
    out4[idx] = v;
}

extern "C" void kernel_launch(void* const* d_in, const int* in_sizes, int n_in,
                              void* d_out, int out_size, void* d_ws, size_t ws_size,
                              hipStream_t stream) {
    const float* x = (const float*)d_in[0];
    float* out = (float*)d_out;
    float2* ws = (float2*)d_ws;

    hipLaunchKernelGGL(topk_kernel, dim3(NBLK), dim3(256), 0, stream, x, out, ws);
    hipLaunchKernelGGL(norm_kernel, dim3(NBLK), dim3(256), 0, stream, out, ws);
}